// Round 5
// baseline (243.392 us; speedup 1.0000x reference)
//
#include <hip/hip_runtime.h>
#include <stdint.h>

#define IN_F 1024
#define OUT_F 1024
#define SCALING 0.25f
#define BLOCK 256
#define RPW 16   // rows per wave
#define DEPTH 4  // prefetch ring depth (4 KB in flight per wave)

typedef float f32x4 __attribute__((ext_vector_type(4)));

// Opaque-asm pin: after this, the value's def is the asm (opaque), so the
// compiler CANNOT rematerialize the original load inside the loop — it must
// keep the value register-resident (or spill, which the 256-VGPR budget
// avoids). R1/R2/R3 all lost their loop-invariant fragments to remat
// (VGPR_Count 68/64/100), and every remat load entering the in-order vmcnt
// queue behind the x-prefetches meant each A/B wait drained the whole x
// pipeline — the mechanism behind the structure-invariant ~2.3 TB/s.
#define PIN4(v) \
  asm volatile("" : "+v"((v).x), "+v"((v).y), "+v"((v).z), "+v"((v).w))

// Fused LoRA rank-4, vmcnt-clean software pipeline.
// Per wave: 16 rows. Loop body i: consume ring[i&3] (64 FMA) -> refill
// ring[i&3] with row i+4 (4 coalesced float4 loads, loop-carried so the
// scheduler cannot sink them to their use) -> 6-stage butterfly (all lanes
// end with h) -> phase-2 (16 FMA) -> 4 nontemporal float4 stores.
// The ONLY vmcnt ops in the loop are x loads and out stores; stores are
// always younger than the loads being waited on, so the prefetch pipeline
// is never drained. A (64 VGPR) + B (64) + ring (64) + temps ~= 216 VGPR
// -> 2 waves/SIMD under __launch_bounds__(256,2).
__global__ __launch_bounds__(BLOCK, 2) void lora_fused(
    const float* __restrict__ x, const float* __restrict__ A,
    const float* __restrict__ B, float* __restrict__ out, int nrows) {
  const int lane = threadIdx.x & 63;
  const int gw = (int)((blockIdx.x * (unsigned)BLOCK + threadIdx.x) >> 6);
  const int row_base = gw * RPW;
  if (row_base >= nrows) return;
  const int last = nrows - 1;

  const float4* __restrict__ X4 = (const float4*)x;
  const float4* __restrict__ A4 = (const float4*)A;
  const float4* __restrict__ B4 = (const float4*)B;
  f32x4* __restrict__ out4 = (f32x4*)out;

  // a[r][k]: A row r, f4-col (lane + 64k).
  float4 a[4][4];
#pragma unroll
  for (int r = 0; r < 4; ++r)
#pragma unroll
    for (int k = 0; k < 4; ++k) a[r][k] = A4[r * 256 + lane + 64 * k];

  // b[k][c]: B row 4*(lane+64k)+c = rank coeffs of output col 4*(lane+64k)+c.
  float4 b[4][4];
#pragma unroll
  for (int k = 0; k < 4; ++k)
#pragma unroll
    for (int c = 0; c < 4; ++c) b[k][c] = B4[4 * (lane + 64 * k) + c];

  // Pin both fragments resident (one-time vmcnt(0) here, then never again).
#pragma unroll
  for (int r = 0; r < 4; ++r)
#pragma unroll
    for (int k = 0; k < 4; ++k) PIN4(a[r][k]);
#pragma unroll
  for (int k = 0; k < 4; ++k)
#pragma unroll
    for (int c = 0; c < 4; ++c) PIN4(b[k][c]);

  // Prologue: fill the ring with rows 0..3 (clamped; nrows=32768 divides
  // evenly so clamps are no-ops in the benchmark shape).
  float4 ring[DEPTH][4];
#pragma unroll
  for (int d = 0; d < DEPTH; ++d) {
    const size_t rr = (size_t)min(row_base + d, last) * 256;
#pragma unroll
    for (int k = 0; k < 4; ++k) ring[d][k] = X4[rr + lane + 64 * k];
  }

#pragma unroll
  for (int i = 0; i < RPW; ++i) {
    const int slot = i & (DEPTH - 1);  // compile-time after unroll

    // Consume ring[slot] (waits only on loads issued 4 iterations ago).
    float p0 = 0.f, p1 = 0.f, p2 = 0.f, p3 = 0.f;
#pragma unroll
    for (int k = 0; k < 4; ++k) {
      const float4 xv = ring[slot][k];
      p0 += xv.x * a[0][k].x + xv.y * a[0][k].y + xv.z * a[0][k].z +
            xv.w * a[0][k].w;
      p1 += xv.x * a[1][k].x + xv.y * a[1][k].y + xv.z * a[1][k].z +
            xv.w * a[1][k].w;
      p2 += xv.x * a[2][k].x + xv.y * a[2][k].y + xv.z * a[2][k].z +
            xv.w * a[2][k].w;
      p3 += xv.x * a[3][k].x + xv.y * a[3][k].y + xv.z * a[3][k].z +
            xv.w * a[3][k].w;
    }

    // Refill slot with row i+DEPTH — issued ~3 iterations (>1800 cyc at
    // 2 waves/SIMD) before its consumption; HBM latency (~900 cyc) covered.
    if (i + DEPTH < RPW) {
      const size_t rr = (size_t)min(row_base + i + DEPTH, last) * 256;
#pragma unroll
      for (int k = 0; k < 4; ++k) ring[slot][k] = X4[rr + lane + 64 * k];
    }

    // Full-wave butterfly: all lanes end with the row sums (phase 2 needs
    // h broadcast anyway).
#pragma unroll
    for (int off = 1; off < 64; off <<= 1) {
      p0 += __shfl_xor(p0, off, 64);
      p1 += __shfl_xor(p1, off, 64);
      p2 += __shfl_xor(p2, off, 64);
      p3 += __shfl_xor(p3, off, 64);
    }

    const int row = row_base + i;
    if (row < nrows) {
      const float h0 = p0 * SCALING, h1 = p1 * SCALING, h2 = p2 * SCALING,
                  h3 = p3 * SCALING;
      const size_t orow = (size_t)row * 256;
#pragma unroll
      for (int k = 0; k < 4; ++k) {
        f32x4 res;
        res.x = h0 * b[k][0].x + h1 * b[k][0].y + h2 * b[k][0].z +
                h3 * b[k][0].w;
        res.y = h0 * b[k][1].x + h1 * b[k][1].y + h2 * b[k][1].z +
                h3 * b[k][1].w;
        res.z = h0 * b[k][2].x + h1 * b[k][2].y + h2 * b[k][2].z +
                h3 * b[k][2].w;
        res.w = h0 * b[k][3].x + h1 * b[k][3].y + h2 * b[k][3].z +
                h3 * b[k][3].w;
        // out is never re-read: don't let 134 MB of writes thrash L3
        // (preserves x's L3 residency across iterations).
        __builtin_nontemporal_store(res, &out4[orow + lane + 64 * k]);
      }
    }
  }
}

extern "C" void kernel_launch(void* const* d_in, const int* in_sizes, int n_in,
                              void* d_out, int out_size, void* d_ws,
                              size_t ws_size, hipStream_t stream) {
  const float* x = (const float*)d_in[0];
  const float* A = (const float*)d_in[1];
  const float* B = (const float*)d_in[2];
  float* out = (float*)d_out;

  const int nrows = in_sizes[0] / IN_F;  // 32768
  const int rows_per_block = RPW * (BLOCK / 64);  // 64
  const int blocks = (nrows + rows_per_block - 1) / rows_per_block;  // 512
  lora_fused<<<blocks, BLOCK, 0, stream>>>(x, A, B, out, nrows);
}